// Round 5
// baseline (1308.787 us; speedup 1.0000x reference)
//
#include <hip/hip_runtime.h>
#include <hip/hip_bf16.h>
#include <math.h>

#define EPS 1e-6f
#define RS3 0.57735026918962576f  /* 1/sqrt(3) */
#define RS2 0.70710678118654752f  /* 1/sqrt(2) */

typedef __attribute__((ext_vector_type(8))) short bf16x8;
typedef __attribute__((ext_vector_type(4))) float f32x4;

__device__ __forceinline__ ushort f2bf(float f) {
  unsigned u = __float_as_uint(f);
  u += 0x7fffu + ((u >> 16) & 1u);      // RNE
  return (ushort)(u >> 16);
}
__device__ __forceinline__ float bf2f(ushort u) {
  return __uint_as_float(((unsigned)u) << 16);
}
__device__ __forceinline__ void split_hl(float v, ushort& h, ushort& l) {
  h = f2bf(v);
  l = f2bf(v - bf2f(h));
}
__device__ __forceinline__ float wave_sum64(float v) {
#pragma unroll
  for (int m = 32; m > 0; m >>= 1) v += __shfl_xor(v, m, 64);
  return v;
}

// ---------------------------------------------------------------------------
// fp32 weights -> bf16 hi/lo (concatenated: W_src|W_dst|W_ff1|W_ffd|W_ff2)
// ---------------------------------------------------------------------------
__global__ __launch_bounds__(256) void cvt_weights_hl(
    const float* __restrict__ w_src, const float* __restrict__ w_dst,
    const float* __restrict__ w_ff1, const float* __restrict__ w_ffd,
    const float* __restrict__ w_ff2, ushort* __restrict__ oh, ushort* __restrict__ ol)
{
  long i = ((long)blockIdx.x * 256 + threadIdx.x) * 8;
  const float* s; long l;
  if      (i < 262144)  { s = w_src; l = i; }
  else if (i < 524288)  { s = w_dst; l = i - 262144; }
  else if (i < 1572864) { s = w_ff1; l = i - 524288; }
  else if (i < 5767168) { s = w_ffd; l = i - 1572864; }
  else                  { s = w_ff2; l = i - 5767168; }
  ushort h[8], lo[8];
#pragma unroll
  for (int j = 0; j < 8; ++j) split_hl(s[l + j], h[j], lo[j]);
  ushort4 h0 = {h[0], h[1], h[2], h[3]}, h1 = {h[4], h[5], h[6], h[7]};
  ushort4 l0 = {lo[0], lo[1], lo[2], lo[3]}, l1 = {lo[4], lo[5], lo[6], lo[7]};
  *(ushort4*)(oh + i) = h0; *(ushort4*)(oh + i + 4) = h1;
  *(ushort4*)(ol + i) = l0; *(ushort4*)(ol + i + 4) = l1;
}

// ---------------------------------------------------------------------------
// Wcomb[p][h*512+c] = sum_{o in [64h,64h+64)} W_proj[p][o]*W_value[o][c] -> hi/lo
// ---------------------------------------------------------------------------
__global__ __launch_bounds__(256) void wcomb_kernel(
    const float* __restrict__ Wp, const float* __restrict__ Wv,
    ushort* __restrict__ oh, ushort* __restrict__ ol)
{
  __shared__ float wp[64 * 65];
  __shared__ float wv[64 * 65];
  const int h = blockIdx.x >> 3, ct = blockIdx.x & 7, pt = blockIdx.y;
  const int t = threadIdx.x;
#pragma unroll
  for (int r = 0; r < 16; ++r) {
    int f = r * 256 + t;
    int p = f >> 6, o = f & 63;
    wp[p * 65 + o] = Wp[(long)(pt * 64 + p) * 512 + h * 64 + o];
  }
#pragma unroll
  for (int r = 0; r < 16; ++r) {
    int f = r * 256 + t;
    int o = f >> 6, c = f & 63;
    wv[o * 65 + c] = Wv[(long)(h * 64 + o) * 512 + ct * 64 + c];
  }
  __syncthreads();
  const int tp = t >> 4, tc = t & 15;
  float acc[4][4] = {};
  for (int o = 0; o < 64; ++o) {
    float av[4], bv[4];
#pragma unroll
    for (int i = 0; i < 4; ++i) av[i] = wp[(tp * 4 + i) * 65 + o];
#pragma unroll
    for (int j = 0; j < 4; ++j) bv[j] = wv[o * 65 + tc * 4 + j];
#pragma unroll
    for (int i = 0; i < 4; ++i)
#pragma unroll
      for (int j = 0; j < 4; ++j) acc[i][j] += av[i] * bv[j];
  }
#pragma unroll
  for (int i = 0; i < 4; ++i) {
    int p = pt * 64 + tp * 4 + i;
    ushort h4[4], l4[4];
#pragma unroll
    for (int j = 0; j < 4; ++j) split_hl(acc[i][j], h4[j], l4[j]);
    ushort4 hv = {h4[0], h4[1], h4[2], h4[3]}, lv = {l4[0], l4[1], l4[2], l4[3]};
    long o = (long)p * 4096 + h * 512 + ct * 64 + tc * 4;
    *(ushort4*)(oh + o) = hv;
    *(ushort4*)(ol + o) = lv;
  }
}

// ---------------------------------------------------------------------------
// Split-precision MFMA GEMM (B pre-split hi/lo ushort): C[j][m]=sum_k A[m][k]B[j][k]
// product = AhBh + AhBl + AlBh. MT: M-tile = 32*MT. 4 waves (2x2).
// B row jj -> (jj/3)*bnp + (jj%3)*K. outmode 0: fp32; 1: hi/lo; 2: both.
// ADD: += ADD[(jj/48)*1536 + (jj%3)*512 + m]
// ---------------------------------------------------------------------------
template<int MT>
__global__ __launch_bounds__(256) void gemm_hl(
    const ushort* __restrict__ AH, const ushort* __restrict__ AL,
    const ushort* __restrict__ BH, const ushort* __restrict__ BL,
    float* __restrict__ Cf, ushort* __restrict__ CH, ushort* __restrict__ CL,
    const float* __restrict__ ADD, int M, int K, long bnp, int outmode)
{
  __shared__ __align__(16) ushort AsH[32 * MT * 72];
  __shared__ __align__(16) ushort AsL[32 * MT * 72];
  __shared__ __align__(16) ushort BsH[96 * 72];
  __shared__ __align__(16) ushort BsL[96 * 72];
  const int t = threadIdx.x;
  const int m0 = blockIdx.x * (32 * MT);
  const int j0 = blockIdx.y * 96;
  const int wid = t >> 6, lane = t & 63;
  const int wm = (wid >> 1) * (16 * MT), wn = (wid & 1) * 48;
  const int r16 = lane & 15, quad = lane >> 4;

  f32x4 acc[MT][3];
#pragma unroll
  for (int i = 0; i < MT; ++i)
#pragma unroll
    for (int j = 0; j < 3; ++j) acc[i][j] = (f32x4){0.f, 0.f, 0.f, 0.f};

  for (int k0 = 0; k0 < K; k0 += 64) {
#pragma unroll
    for (int r = 0; r < MT; ++r) {
      int f = r * 256 + t;
      int m = f >> 3, kc = f & 7;
      long off = (long)(m0 + m) * K + k0 + kc * 8;
      *(uint4*)(AsH + m * 72 + kc * 8) = *(const uint4*)(AH + off);
      *(uint4*)(AsL + m * 72 + kc * 8) = *(const uint4*)(AL + off);
    }
#pragma unroll
    for (int r = 0; r < 3; ++r) {
      int f = r * 256 + t;
      int n = f >> 3, kc = f & 7;
      int jj = j0 + n;
      int bq = jj / 3, xr = jj - bq * 3;
      long off = (long)bq * bnp + (long)xr * K + k0 + kc * 8;
      *(uint4*)(BsH + n * 72 + kc * 8) = *(const uint4*)(BH + off);
      *(uint4*)(BsL + n * 72 + kc * 8) = *(const uint4*)(BL + off);
    }
    __syncthreads();
#pragma unroll
    for (int kh = 0; kh < 2; ++kh) {
      bf16x8 ah[MT], al[MT], bh[3], bl[3];
#pragma unroll
      for (int i = 0; i < MT; ++i) {
        int ro = (wm + i * 16 + r16) * 72 + kh * 32 + quad * 8;
        ah[i] = *(const bf16x8*)(AsH + ro);
        al[i] = *(const bf16x8*)(AsL + ro);
      }
#pragma unroll
      for (int j = 0; j < 3; ++j) {
        int ro = (wn + j * 16 + r16) * 72 + kh * 32 + quad * 8;
        bh[j] = *(const bf16x8*)(BsH + ro);
        bl[j] = *(const bf16x8*)(BsL + ro);
      }
#pragma unroll
      for (int i = 0; i < MT; ++i)
#pragma unroll
        for (int j = 0; j < 3; ++j) {
          acc[i][j] = __builtin_amdgcn_mfma_f32_16x16x32_bf16(ah[i], bh[j], acc[i][j], 0, 0, 0);
          acc[i][j] = __builtin_amdgcn_mfma_f32_16x16x32_bf16(ah[i], bl[j], acc[i][j], 0, 0, 0);
          acc[i][j] = __builtin_amdgcn_mfma_f32_16x16x32_bf16(al[i], bh[j], acc[i][j], 0, 0, 0);
        }
    }
    __syncthreads();
  }

#pragma unroll
  for (int j = 0; j < 3; ++j) {
    int jj = j0 + wn + j * 16 + r16;
    const float* ap = ADD ? (ADD + (long)(jj / 48) * 1536 + (jj % 3) * 512) : nullptr;
#pragma unroll
    for (int i = 0; i < MT; ++i) {
      int mm = m0 + wm + i * 16 + quad * 4;
      f32x4 v = acc[i][j];
      if (ap) { v.x += ap[mm]; v.y += ap[mm + 1]; v.z += ap[mm + 2]; v.w += ap[mm + 3]; }
      long o = (long)jj * M + mm;
      if (outmode != 1) *(f32x4*)(Cf + o) = v;
      if (outmode != 0) {
        ushort h[4], l[4];
        split_hl(v.x, h[0], l[0]); split_hl(v.y, h[1], l[1]);
        split_hl(v.z, h[2], l[2]); split_hl(v.w, h[3], l[3]);
        ushort4 hv = {h[0], h[1], h[2], h[3]}, lv = {l[0], l[1], l[2], l[3]};
        *(ushort4*)(CH + o) = hv;
        *(ushort4*)(CL + o) = lv;
      }
    }
  }
}

// ---------------------------------------------------------------------------
// Same GEMM but B staged directly from interleaved fp32 [b][K][3]:
// B[jj][k] = Bf[(jj/3)*3K + k*3 + (jj%3)], split to hi/lo during staging.
// ---------------------------------------------------------------------------
template<int MT>
__global__ __launch_bounds__(256) void gemm_hlf(
    const ushort* __restrict__ AH, const ushort* __restrict__ AL,
    const float* __restrict__ Bf,
    float* __restrict__ Cf, ushort* __restrict__ CH, ushort* __restrict__ CL,
    const float* __restrict__ ADD, int M, int K, int outmode)
{
  __shared__ __align__(16) ushort AsH[32 * MT * 72];
  __shared__ __align__(16) ushort AsL[32 * MT * 72];
  __shared__ __align__(16) ushort BsH[96 * 72];
  __shared__ __align__(16) ushort BsL[96 * 72];
  const int t = threadIdx.x;
  const int m0 = blockIdx.x * (32 * MT);
  const int j0 = blockIdx.y * 96;
  const int wid = t >> 6, lane = t & 63;
  const int wm = (wid >> 1) * (16 * MT), wn = (wid & 1) * 48;
  const int r16 = lane & 15, quad = lane >> 4;

  f32x4 acc[MT][3];
#pragma unroll
  for (int i = 0; i < MT; ++i)
#pragma unroll
    for (int j = 0; j < 3; ++j) acc[i][j] = (f32x4){0.f, 0.f, 0.f, 0.f};

  for (int k0 = 0; k0 < K; k0 += 64) {
#pragma unroll
    for (int r = 0; r < MT; ++r) {
      int f = r * 256 + t;
      int m = f >> 3, kc = f & 7;
      long off = (long)(m0 + m) * K + k0 + kc * 8;
      *(uint4*)(AsH + m * 72 + kc * 8) = *(const uint4*)(AH + off);
      *(uint4*)(AsL + m * 72 + kc * 8) = *(const uint4*)(AL + off);
    }
#pragma unroll
    for (int r = 0; r < 3; ++r) {
      int f = r * 256 + t;
      int n = f >> 3, kc = f & 7;
      int jj = j0 + n;
      int bq = jj / 3, xr = jj - bq * 3;
      const float* bp = Bf + (long)bq * (3 * K) + (long)(k0 + kc * 8) * 3 + xr;
      ushort hh[8], ll[8];
#pragma unroll
      for (int i = 0; i < 8; ++i) split_hl(bp[i * 3], hh[i], ll[i]);
      *(ushort4*)(BsH + n * 72 + kc * 8)     = *(ushort4*)hh;
      *(ushort4*)(BsH + n * 72 + kc * 8 + 4) = *(ushort4*)(hh + 4);
      *(ushort4*)(BsL + n * 72 + kc * 8)     = *(ushort4*)ll;
      *(ushort4*)(BsL + n * 72 + kc * 8 + 4) = *(ushort4*)(ll + 4);
    }
    __syncthreads();
#pragma unroll
    for (int kh = 0; kh < 2; ++kh) {
      bf16x8 ah[MT], al[MT], bh[3], bl[3];
#pragma unroll
      for (int i = 0; i < MT; ++i) {
        int ro = (wm + i * 16 + r16) * 72 + kh * 32 + quad * 8;
        ah[i] = *(const bf16x8*)(AsH + ro);
        al[i] = *(const bf16x8*)(AsL + ro);
      }
#pragma unroll
      for (int j = 0; j < 3; ++j) {
        int ro = (wn + j * 16 + r16) * 72 + kh * 32 + quad * 8;
        bh[j] = *(const bf16x8*)(BsH + ro);
        bl[j] = *(const bf16x8*)(BsL + ro);
      }
#pragma unroll
      for (int i = 0; i < MT; ++i)
#pragma unroll
        for (int j = 0; j < 3; ++j) {
          acc[i][j] = __builtin_amdgcn_mfma_f32_16x16x32_bf16(ah[i], bh[j], acc[i][j], 0, 0, 0);
          acc[i][j] = __builtin_amdgcn_mfma_f32_16x16x32_bf16(ah[i], bl[j], acc[i][j], 0, 0, 0);
          acc[i][j] = __builtin_amdgcn_mfma_f32_16x16x32_bf16(al[i], bh[j], acc[i][j], 0, 0, 0);
        }
    }
    __syncthreads();
  }

#pragma unroll
  for (int j = 0; j < 3; ++j) {
    int jj = j0 + wn + j * 16 + r16;
    const float* ap = ADD ? (ADD + (long)(jj / 48) * 1536 + (jj % 3) * 512) : nullptr;
#pragma unroll
    for (int i = 0; i < MT; ++i) {
      int mm = m0 + wm + i * 16 + quad * 4;
      f32x4 v = acc[i][j];
      if (ap) { v.x += ap[mm]; v.y += ap[mm + 1]; v.z += ap[mm + 2]; v.w += ap[mm + 3]; }
      long o = (long)jj * M + mm;
      if (outmode != 1) *(f32x4*)(Cf + o) = v;
      if (outmode != 0) {
        ushort h[4], l[4];
        split_hl(v.x, h[0], l[0]); split_hl(v.y, h[1], l[1]);
        split_hl(v.z, h[2], l[2]); split_hl(v.w, h[3], l[3]);
        ushort4 hv = {h[0], h[1], h[2], h[3]}, lv = {l[0], l[1], l[2], l[3]};
        *(ushort4*)(CH + o) = hv;
        *(ushort4*)(CL + o) = lv;
      }
    }
  }
}

// ---------------------------------------------------------------------------
// Fused edge + attention kernel. 1 block = 1 node n (16 edges), 256 threads.
// Phases: MLP(16 edges) -> w[16][1536] (LDS) -> read msg, psc(LDS)+pv(regs)
// -> psc@W_alpha GEMV + LN + head-dot -> softmax -> aggregate pv (regs)
// -> write pvagg hi/lo IN PLACE into this block's own msg slice.
// pvagg row (n,x) at ushort offset n*24576 + x*4096 + h*512 + c.
// ---------------------------------------------------------------------------
__global__ __launch_bounds__(256, 1) void edge_attn(
    ushort* __restrict__ msgH, ushort* __restrict__ msgL,
    const float* __restrict__ edge_sh, const float* __restrict__ edge_scalars,
    const float* __restrict__ fc_w1, const float* __restrict__ fc_b1,
    const float* __restrict__ fc_w2, const float* __restrict__ fc_b2,
    const float* __restrict__ fc_w3, const float* __restrict__ fc_b3,
    const float* __restrict__ W_alpha, const float* __restrict__ ln_g,
    const float* __restrict__ ln_b, const float* __restrict__ alpha_dot)
{
  __shared__ float w_all[16 * 1536];   // 98304 B
  __shared__ float psc[16 * 512];      // 32768 B (early: fc_w1|fc_w2|b1|b2 stage)
  __shared__ float esl[16 * 64];       // 4096
  __shared__ float h1l[16 * 32];       // 2048
  __shared__ float h2l[16 * 32];       // 2048
  __shared__ float shl[16 * 4];        // 256
  __shared__ float atl[16 * 8];        // 512

  const int t = threadIdx.x;
  const int n = blockIdx.x;
  const int e0 = n * 16;
  const int lane = t & 63, wvi = t >> 6;

  // --- A0: stage ---
#pragma unroll
  for (int r = 0; r < 4; ++r)
    esl[t + 256 * r] = edge_scalars[(long)e0 * 64 + t + 256 * r];
  if (t < 64) shl[t] = edge_sh[(long)e0 * 4 + t];
#pragma unroll
  for (int r = 0; r < 13; ++r) {
    int l = t + 256 * r;
    if (l < 2048)      psc[l] = fc_w1[l];
    else if (l < 3072) psc[l] = fc_w2[l - 2048];
    else if (l < 3104) psc[l] = fc_b1[l - 3072];
    else if (l < 3136) psc[l] = fc_b2[l - 3104];
  }
  __syncthreads();

  // --- A1: MLP layer 1 (16 e x 32 j = 512 tasks) ---
#pragma unroll
  for (int it = 0; it < 2; ++it) {
    int l = t + 256 * it;
    int e = l >> 5, j = l & 31;
    float v = psc[3072 + j];
#pragma unroll 8
    for (int i = 0; i < 64; ++i) v += esl[e * 64 + i] * psc[i * 32 + j];
    h1l[e * 32 + j] = v / (1.f + expf(-v));
  }
  __syncthreads();
#pragma unroll
  for (int it = 0; it < 2; ++it) {
    int l = t + 256 * it;
    int e = l >> 5, j = l & 31;
    float v = psc[3104 + j];
#pragma unroll 8
    for (int i = 0; i < 32; ++i) v += h1l[e * 32 + i] * psc[2048 + i * 32 + j];
    h2l[e * 32 + j] = v / (1.f + expf(-v));
  }
  __syncthreads();

  // --- B: w[e][cc] for all 16 edges; fc_w3 read once per block ---
  {
    float wacc[16][6];
#pragma unroll
    for (int q = 0; q < 6; ++q) {
      float b3 = fc_b3[t + 256 * q];
#pragma unroll
      for (int e = 0; e < 16; ++e) wacc[e][q] = b3;
    }
    for (int j = 0; j < 32; ++j) {
      float w3[6];
#pragma unroll
      for (int q = 0; q < 6; ++q) w3[q] = fc_w3[j * 1536 + t + 256 * q];
#pragma unroll
      for (int e = 0; e < 16; ++e) {
        float h2 = h2l[e * 32 + j];
#pragma unroll
        for (int q = 0; q < 6; ++q) wacc[e][q] += h2 * w3[q];
      }
    }
#pragma unroll
    for (int e = 0; e < 16; ++e)
#pragma unroll
      for (int q = 0; q < 6; ++q)
        w_all[e * 1536 + t + 256 * q] = wacc[e][q];
  }
  __syncthreads();   // w ready; psc area free to overwrite

  // --- C: read msg, compute psc -> LDS, pv -> registers ---
  const int c0 = t * 2;
  float pvr[16][6];
#pragma unroll
  for (int k = 0; k < 16; ++k) {
    const long eb = (long)(e0 + k) * 1536;
    const float s  = shl[k * 4 + 0], vx = shl[k * 4 + 1],
                vy = shl[k * 4 + 2], vz = shl[k * 4 + 3];
    float2 w0p = *(const float2*)&w_all[k * 1536 + c0];
    float2 w1p = *(const float2*)&w_all[k * 1536 + 512 + c0];
    float2 w2p = *(const float2*)&w_all[k * 1536 + 1024 + c0];
    float pout[2];
#pragma unroll
    for (int ci = 0; ci < 2; ++ci) {
      int c = c0 + ci;
      float m0 = bf2f(msgH[eb + c])        + bf2f(msgL[eb + c]);
      float m1 = bf2f(msgH[eb + 512 + c])  + bf2f(msgL[eb + 512 + c]);
      float m2 = bf2f(msgH[eb + 1024 + c]) + bf2f(msgL[eb + 1024 + c]);
      float w0 = ci ? w0p.y : w0p.x;
      float w1 = ci ? w1p.y : w1p.x;
      float w2 = ci ? w2p.y : w2p.x;
      float dotv = m0 * vx + m1 * vy + m2 * vz;
      pout[ci] = w0 * dotv * RS3;
      float cx = m1 * vz - m2 * vy;
      float cy = m2 * vx - m0 * vz;
      float cz = m0 * vy - m1 * vx;
      float f1 = w1 * s, f2 = w2 * RS2;
      pvr[k][ci * 3 + 0] = f1 * m0 + f2 * cx;
      pvr[k][ci * 3 + 1] = f1 * m1 + f2 * cy;
      pvr[k][ci * 3 + 2] = f1 * m2 + f2 * cz;
    }
    *(float2*)&psc[k * 512 + c0] = make_float2(pout[0], pout[1]);
  }
  __syncthreads();

  // --- D: GEMV psc @ W_alpha (wave wvi owns k = 4*wvi..4*wvi+3), LN, head dot ---
  {
    float accm[4] = {0.f, 0.f, 0.f, 0.f};
    const int kb = wvi * 4;
#pragma unroll 8
    for (int c = 0; c < 512; ++c) {
      float wa = W_alpha[c * 64 + lane];
#pragma unroll
      for (int q = 0; q < 4; ++q) accm[q] += psc[(kb + q) * 512 + c] * wa;
    }
    float lg = ln_g[lane], lb = ln_b[lane], ad = alpha_dot[lane];
#pragma unroll
    for (int q = 0; q < 4; ++q) {
      float a = accm[q];
      float s1 = wave_sum64(a);
      float s2 = wave_sum64(a * a);
      float mu  = s1 * (1.f / 64.f);
      float var = s2 * (1.f / 64.f) - mu * mu;
      float aln = (a - mu) * rsqrtf(var + EPS) * lg + lb;
      float act = 0.6f * aln + 0.4f * aln * tanhf(0.5f * aln);
      float p = act * ad;
#pragma unroll
      for (int d2 = 4; d2 > 0; d2 >>= 1) p += __shfl_down(p, d2, 8);
      if ((lane & 7) == 0) atl[(kb + q) * 8 + (lane >> 3)] = p;
    }
  }
  __syncthreads();

  // --- D2: softmax over k per head ---
  if (t < 8) {
    int h = t;
    float mx = -1e30f;
    for (int k = 0; k < 16; ++k) mx = fmaxf(mx, atl[k * 8 + h]);
    float ex[16], sm = 0.f;
    for (int k = 0; k < 16; ++k) { ex[k] = expf(atl[k * 8 + h] - mx); sm += ex[k]; }
    float inv = 1.f / sm;
    for (int k = 0; k < 16; ++k) atl[k * 8 + h] = ex[k] * inv;
  }
  __syncthreads();

  // --- E: aggregate pv over k with attn weights ---
  float agg[8][6];
#pragma unroll
  for (int h = 0; h < 8; ++h)
#pragma unroll
    for (int q = 0; q < 6; ++q) agg[h][q] = 0.f;
#pragma unroll
  for (int k = 0; k < 16; ++k) {
    float aw[8];
#pragma unroll
    for (int h = 0; h < 8; ++h) aw[h] = atl[k * 8 + h];
#pragma unroll
    for (int h = 0; h < 8; ++h)
#pragma unroll
      for (int q = 0; q < 6; ++q) agg[h][q] += aw[h] * pvr[k][q];
  }

  // --- F: write pvagg hi/lo into own msg slice ---
  const long ob = (long)n * 24576;
#pragma unroll
  for (int x = 0; x < 3; ++x)
#pragma unroll
    for (int h = 0; h < 8; ++h) {
      float v0 = agg[h][x], v1 = agg[h][3 + x];
      ushort h0, l0, h1, l1;
      split_hl(v0, h0, l0); split_hl(v1, h1, l1);
      long o = ob + x * 4096 + h * 512 + c0;
      ushort2 uh; uh.x = h0; uh.y = h1;
      ushort2 ul; ul.x = l0; ul.y = l1;
      *(ushort2*)(msgH + o) = uh;
      *(ushort2*)(msgL + o) = ul;
    }
}

// ---------------------------------------------------------------------------
// vn_ln on xC layout. mode 0: outf fp32 xC + hi/lo xC; mode 1: outf [c*3+x]
// ---------------------------------------------------------------------------
__global__ __launch_bounds__(256) void vn_ln_x(
    const float* __restrict__ A, const float* __restrict__ Bp,
    const float* __restrict__ g, const float* __restrict__ bb,
    float* __restrict__ outf, ushort* __restrict__ outH, ushort* __restrict__ outL,
    int mode)
{
  const int n = blockIdx.x, t = threadIdx.x;
  const long base = (long)n * 1536;
  float xv[2][3], nrm[2];
#pragma unroll
  for (int q = 0; q < 2; ++q) {
    int c = t + 256 * q;
    float ssq = 0.f;
#pragma unroll
    for (int x = 0; x < 3; ++x) {
      float v = A[base + x * 512 + c] + Bp[base + x * 512 + c];
      xv[q][x] = v; ssq += v * v;
    }
    nrm[q] = sqrtf(ssq + EPS);
  }
  float s1 = nrm[0] + nrm[1];
  float s2 = nrm[0] * nrm[0] + nrm[1] * nrm[1];
  s1 = wave_sum64(s1); s2 = wave_sum64(s2);
  __shared__ float red[8];
  int wid = t >> 6;
  if ((t & 63) == 0) { red[wid] = s1; red[4 + wid] = s2; }
  __syncthreads();
  float S1 = red[0] + red[1] + red[2] + red[3];
  float S2 = red[4] + red[5] + red[6] + red[7];
  float mu  = S1 * (1.f / 512.f);
  float var = S2 * (1.f / 512.f) - mu * mu;
  float rstd = rsqrtf(var + EPS);
#pragma unroll
  for (int q = 0; q < 2; ++q) {
    int c = t + 256 * q;
    float ln = (nrm[q] - mu) * rstd * g[c] + bb[c];
    float sc = ln / nrm[q];
    if (mode == 0) {
#pragma unroll
      for (int x = 0; x < 3; ++x) {
        float v = xv[q][x] * sc;
        outf[base + x * 512 + c] = v;
        ushort h, lo; split_hl(v, h, lo);
        outH[base + x * 512 + c] = h;
        outL[base + x * 512 + c] = lo;
      }
    } else {
#pragma unroll
      for (int x = 0; x < 3; ++x)
        outf[base + c * 3 + x] = xv[q][x] * sc;
    }
  }
}

// ---------------------------------------------------------------------------
// Gate on fp32 y, dvec (xC [n][3][2048]) -> gy hi/lo
// ---------------------------------------------------------------------------
__global__ __launch_bounds__(256) void gate_hl(
    const float* __restrict__ y, const float* __restrict__ dv,
    ushort* __restrict__ gh, ushort* __restrict__ gl)
{
  long idx = (long)blockIdx.x * 256 + threadIdx.x;   // over 1024*2048
  long n = idx >> 11; int o = idx & 2047;
  long b = n * 6144 + o;
  float y0 = y[b], y1 = y[b + 2048], y2 = y[b + 4096];
  float d0 = dv[b], d1 = dv[b + 2048], d2 = dv[b + 4096];
  float dot = y0 * d0 + y1 * d1 + y2 * d2;
  if (dot < 0.f) {
    float dnn = d0 * d0 + d1 * d1 + d2 * d2 + EPS;
    float coef = 0.8f * dot / dnn;
    y0 -= coef * d0; y1 -= coef * d1; y2 -= coef * d2;
  }
  ushort h, lo;
  split_hl(y0, h, lo); gh[b] = h;        gl[b] = lo;
  split_hl(y1, h, lo); gh[b + 2048] = h; gl[b + 2048] = lo;
  split_hl(y2, h, lo); gh[b + 4096] = h; gl[b + 4096] = lo;
}

// ---------------------------------------------------------------------------
extern "C" void kernel_launch(void* const* d_in, const int* in_sizes, int n_in,
                              void* d_out, int out_size, void* d_ws, size_t ws_size,
                              hipStream_t stream)
{
  const float* tgt          = (const float*)d_in[0];
  const float* memory       = (const float*)d_in[1];
  const float* edge_sh      = (const float*)d_in[2];
  const float* edge_scalars = (const float*)d_in[3];
  const float* W_src   = (const float*)d_in[4];
  const float* W_dst   = (const float*)d_in[5];
  const float* fc_w1   = (const float*)d_in[6];
  const float* fc_b1   = (const float*)d_in[7];
  const float* fc_w2   = (const float*)d_in[8];
  const float* fc_b2   = (const float*)d_in[9];
  const float* fc_w3   = (const float*)d_in[10];
  const float* fc_b3   = (const float*)d_in[11];
  const float* W_alpha = (const float*)d_in[12];
  const float* ln_a_g  = (const float*)d_in[13];
  const float* ln_a_b  = (const float*)d_in[14];
  const float* alpha_dot = (const float*)d_in[15];
  const float* W_value = (const float*)d_in[16];
  const float* W_proj  = (const float*)d_in[17];
  const float* n1_g    = (const float*)d_in[18];
  const float* n1_b    = (const float*)d_in[19];
  const float* n2_g    = (const float*)d_in[20];
  const float* n2_b    = (const float*)d_in[21];
  const float* W_ff1   = (const float*)d_in[22];
  const float* W_ffd   = (const float*)d_in[23];
  const float* W_ff2   = (const float*)d_in[24];
  float* out = (float*)d_out;

  char* ws = (char*)d_ws;
  // Region A [0, 100663296): msg hi/lo -> (in-place) pvagg; later FF bufs
  ushort* msgH = (ushort*)(ws + 0);          // 50,331,648 B
  ushort* msgL = (ushort*)(ws + 50331648);   // 50,331,648 B
  float*  yf   = (float*)(ws + 0);           // 25,165,824 B (after pvagg dead)
  ushort* yH   = (ushort*)(ws + 25165824);   // 12,582,912
  ushort* yL   = (ushort*)(ws + 37748736);   // 12,582,912
  float*  dvf  = (float*)(ws + 50331648);    // 25,165,824
  ushort* gyH  = (ushort*)(ws + 75497472);   // 12,582,912
  ushort* gyL  = (ushort*)(ws + 88080384);   // 12,582,912
  // Fixed
  float*  tvx  = (float*)(ws + 100663296);   // 6,291,456
  float*  nb2  = (float*)(ws + 106954752);   // 6,291,456
  // x1 region
  float*  x1f   = (float*)(ws + 113246208);  // 6,291,456
  ushort* x1H   = (ushort*)(ws + 119537664); // 3,145,728
  ushort* x1L   = (ushort*)(ws + 122683392); // 3,145,728
  // Weights
  ushort* WH    = (ushort*)(ws + 126353408); // 13,631,488
  ushort* WL    = (ushort*)(ws + 139984896); // 13,631,488
  ushort* wcH   = (ushort*)(ws + 153616384); // 4,194,304
  ushort* wcL   = (ushort*)(ws + 157810688); // 4,194,304  -> peak 162,004,992 B

  const long SRC = 0, DST = 262144, FF1 = 524288, FFD = 1572864, FF2 = 5767168;

  // prep
  cvt_weights_hl<<<3328, 256, 0, stream>>>(W_src, W_dst, W_ff1, W_ffd, W_ff2, WH, WL);
  wcomb_kernel<<<dim3(64, 8), 256, 0, stream>>>(W_proj, W_value, wcH, wcL);

  // 1. tv = W_dst @ tgt  (fp32 B direct)
  gemm_hlf<2><<<dim3(8, 32), 256, 0, stream>>>(WH + DST, WL + DST, tgt,
      tvx, nullptr, nullptr, nullptr, 512, 512, 0);

  // 2. msg = W_src @ memory + tv  (fp32 B direct, single dispatch, hi/lo out)
  gemm_hlf<4><<<dim3(4, 512), 256, 0, stream>>>(WH + SRC, WL + SRC, memory,
      nullptr, msgH, msgL, tvx, 512, 512, 1);

  // 3. fused edge + attention -> pvagg hi/lo in place (bnp 24576)
  edge_attn<<<1024, 256, 0, stream>>>(msgH, msgL, edge_sh, edge_scalars,
      fc_w1, fc_b1, fc_w2, fc_b2, fc_w3, fc_b3, W_alpha, ln_a_g, ln_a_b, alpha_dot);

  // 4. out3 = Wcomb @ pvagg  (fp32)
  gemm_hl<2><<<dim3(8, 32), 256, 0, stream>>>(wcH, wcL, msgH, msgL,
      nb2, nullptr, nullptr, nullptr, 512, 4096, 24576, 0);

  // 5. x1 = vn_ln(tv + out3): fp32 + hi/lo
  vn_ln_x<<<1024, 256, 0, stream>>>(tvx, nb2, n1_g, n1_b, x1f, x1H, x1L, 0);

  // 6. y = W_ff1 @ x1  (fp32 + hi/lo out; region A dead)
  gemm_hl<4><<<dim3(16, 32), 256, 0, stream>>>(WH + FF1, WL + FF1, x1H, x1L,
      yf, yH, yL, nullptr, 2048, 512, 1536, 2);

  // 7. dvec = W_ffd @ y  (fp32)
  gemm_hl<4><<<dim3(16, 32), 256, 0, stream>>>(WH + FFD, WL + FFD, yH, yL,
      dvf, nullptr, nullptr, nullptr, 2048, 2048, 6144, 0);

  // 8. gate -> gy hi/lo
  gate_hl<<<8192, 256, 0, stream>>>(yf, dvf, gyH, gyL);

  // 9. y2 = W_ff2 @ gy  (fp32, reuse nb2)
  gemm_hl<2><<<dim3(8, 32), 256, 0, stream>>>(WH + FF2, WL + FF2, gyH, gyL,
      nb2, nullptr, nullptr, nullptr, 512, 2048, 6144, 0);

  // 10. out = vn_ln(x1 + y2) -> interleaved [n][c][3]
  vn_ln_x<<<1024, 256, 0, stream>>>(x1f, nb2, n2_g, n2_b, out, nullptr, nullptr, 1);
}

// Round 6
// 818.233 us; speedup vs baseline: 1.5995x; 1.5995x over previous
//
#include <hip/hip_runtime.h>
#include <hip/hip_bf16.h>
#include <math.h>

#define EPS 1e-6f
#define RS3 0.57735026918962576f  /* 1/sqrt(3) */
#define RS2 0.70710678118654752f  /* 1/sqrt(2) */

typedef __attribute__((ext_vector_type(8))) short bf16x8;
typedef __attribute__((ext_vector_type(4))) float f32x4;

__device__ __forceinline__ ushort f2bf(float f) {
  unsigned u = __float_as_uint(f);
  u += 0x7fffu + ((u >> 16) & 1u);      // RNE
  return (ushort)(u >> 16);
}
__device__ __forceinline__ float bf2f(ushort u) {
  return __uint_as_float(((unsigned)u) << 16);
}
__device__ __forceinline__ void split_hl(float v, ushort& h, ushort& l) {
  h = f2bf(v);
  l = f2bf(v - bf2f(h));
}
__device__ __forceinline__ float wave_sum64(float v) {
#pragma unroll
  for (int m = 32; m > 0; m >>= 1) v += __shfl_xor(v, m, 64);
  return v;
}

// ---------------------------------------------------------------------------
// fp32 weights -> bf16 hi/lo (concatenated: W_src|W_dst|W_ff1|W_ffd|W_ff2)
// ---------------------------------------------------------------------------
__global__ __launch_bounds__(256) void cvt_weights_hl(
    const float* __restrict__ w_src, const float* __restrict__ w_dst,
    const float* __restrict__ w_ff1, const float* __restrict__ w_ffd,
    const float* __restrict__ w_ff2, ushort* __restrict__ oh, ushort* __restrict__ ol)
{
  long i = ((long)blockIdx.x * 256 + threadIdx.x) * 8;
  const float* s; long l;
  if      (i < 262144)  { s = w_src; l = i; }
  else if (i < 524288)  { s = w_dst; l = i - 262144; }
  else if (i < 1572864) { s = w_ff1; l = i - 524288; }
  else if (i < 5767168) { s = w_ffd; l = i - 1572864; }
  else                  { s = w_ff2; l = i - 5767168; }
  ushort h[8], lo[8];
#pragma unroll
  for (int j = 0; j < 8; ++j) split_hl(s[l + j], h[j], lo[j]);
  ushort4 h0 = {h[0], h[1], h[2], h[3]}, h1 = {h[4], h[5], h[6], h[7]};
  ushort4 l0 = {lo[0], lo[1], lo[2], lo[3]}, l1 = {lo[4], lo[5], lo[6], lo[7]};
  *(uint4*)(oh + i) = *(uint4*)&h0; *(uint4*)(oh + i + 4) = *(uint4*)&h1;
  *(uint4*)(ol + i) = *(uint4*)&l0; *(uint4*)(ol + i + 4) = *(uint4*)&l1;
}

// ---------------------------------------------------------------------------
// Wcomb[p][h*512+c] = sum_{o in [64h,64h+64)} W_proj[p][o]*W_value[o][c] -> hi/lo
// ---------------------------------------------------------------------------
__global__ __launch_bounds__(256) void wcomb_kernel(
    const float* __restrict__ Wp, const float* __restrict__ Wv,
    ushort* __restrict__ oh, ushort* __restrict__ ol)
{
  __shared__ float wp[64 * 65];
  __shared__ float wv[64 * 65];
  const int h = blockIdx.x >> 3, ct = blockIdx.x & 7, pt = blockIdx.y;
  const int t = threadIdx.x;
#pragma unroll
  for (int r = 0; r < 16; ++r) {
    int f = r * 256 + t;
    int p = f >> 6, o = f & 63;
    wp[p * 65 + o] = Wp[(long)(pt * 64 + p) * 512 + h * 64 + o];
  }
#pragma unroll
  for (int r = 0; r < 16; ++r) {
    int f = r * 256 + t;
    int o = f >> 6, c = f & 63;
    wv[o * 65 + c] = Wv[(long)(h * 64 + o) * 512 + ct * 64 + c];
  }
  __syncthreads();
  const int tp = t >> 4, tc = t & 15;
  float acc[4][4] = {};
  for (int o = 0; o < 64; ++o) {
    float av[4], bv[4];
#pragma unroll
    for (int i = 0; i < 4; ++i) av[i] = wp[(tp * 4 + i) * 65 + o];
#pragma unroll
    for (int j = 0; j < 4; ++j) bv[j] = wv[o * 65 + tc * 4 + j];
#pragma unroll
    for (int i = 0; i < 4; ++i)
#pragma unroll
      for (int j = 0; j < 4; ++j) acc[i][j] += av[i] * bv[j];
  }
#pragma unroll
  for (int i = 0; i < 4; ++i) {
    int p = pt * 64 + tp * 4 + i;
    ushort h4[4], l4[4];
#pragma unroll
    for (int j = 0; j < 4; ++j) split_hl(acc[i][j], h4[j], l4[j]);
    ushort4 hv = {h4[0], h4[1], h4[2], h4[3]}, lv = {l4[0], l4[1], l4[2], l4[3]};
    long o = (long)p * 4096 + h * 512 + ct * 64 + tc * 4;
    *(ushort4*)(oh + o) = hv;
    *(ushort4*)(ol + o) = lv;
  }
}

// ---------------------------------------------------------------------------
// Split-precision MFMA GEMM (B pre-split hi/lo ushort): C[j][m]=sum_k A[m][k]B[j][k]
// product = AhBh + AhBl + AlBh. MT: M-tile = 32*MT. 4 waves (2x2).
// B row jj -> (jj/3)*bnp + (jj%3)*K. outmode 0: fp32; 1: hi/lo; 2: both.
// ADD: += ADD[(jj/48)*1536 + (jj%3)*512 + m]
// ---------------------------------------------------------------------------
template<int MT>
__global__ __launch_bounds__(256) void gemm_hl(
    const ushort* __restrict__ AH, const ushort* __restrict__ AL,
    const ushort* __restrict__ BH, const ushort* __restrict__ BL,
    float* __restrict__ Cf, ushort* __restrict__ CH, ushort* __restrict__ CL,
    const float* __restrict__ ADD, int M, int K, long bnp, int outmode)
{
  __shared__ __align__(16) ushort AsH[32 * MT * 72];
  __shared__ __align__(16) ushort AsL[32 * MT * 72];
  __shared__ __align__(16) ushort BsH[96 * 72];
  __shared__ __align__(16) ushort BsL[96 * 72];
  const int t = threadIdx.x;
  const int m0 = blockIdx.x * (32 * MT);
  const int j0 = blockIdx.y * 96;
  const int wid = t >> 6, lane = t & 63;
  const int wm = (wid >> 1) * (16 * MT), wn = (wid & 1) * 48;
  const int r16 = lane & 15, quad = lane >> 4;

  f32x4 acc[MT][3];
#pragma unroll
  for (int i = 0; i < MT; ++i)
#pragma unroll
    for (int j = 0; j < 3; ++j) acc[i][j] = (f32x4){0.f, 0.f, 0.f, 0.f};

  for (int k0 = 0; k0 < K; k0 += 64) {
#pragma unroll
    for (int r = 0; r < MT; ++r) {
      int f = r * 256 + t;
      int m = f >> 3, kc = f & 7;
      long off = (long)(m0 + m) * K + k0 + kc * 8;
      *(uint4*)(AsH + m * 72 + kc * 8) = *(const uint4*)(AH + off);
      *(uint4*)(AsL + m * 72 + kc * 8) = *(const uint4*)(AL + off);
    }
#pragma unroll
    for (int r = 0; r < 3; ++r) {
      int f = r * 256 + t;
      int n = f >> 3, kc = f & 7;
      int jj = j0 + n;
      int bq = jj / 3, xr = jj - bq * 3;
      long off = (long)bq * bnp + (long)xr * K + k0 + kc * 8;
      *(uint4*)(BsH + n * 72 + kc * 8) = *(const uint4*)(BH + off);
      *(uint4*)(BsL + n * 72 + kc * 8) = *(const uint4*)(BL + off);
    }
    __syncthreads();
#pragma unroll
    for (int kh = 0; kh < 2; ++kh) {
      bf16x8 ah[MT], al[MT], bh[3], bl[3];
#pragma unroll
      for (int i = 0; i < MT; ++i) {
        int ro = (wm + i * 16 + r16) * 72 + kh * 32 + quad * 8;
        ah[i] = *(const bf16x8*)(AsH + ro);
        al[i] = *(const bf16x8*)(AsL + ro);
      }
#pragma unroll
      for (int j = 0; j < 3; ++j) {
        int ro = (wn + j * 16 + r16) * 72 + kh * 32 + quad * 8;
        bh[j] = *(const bf16x8*)(BsH + ro);
        bl[j] = *(const bf16x8*)(BsL + ro);
      }
#pragma unroll
      for (int i = 0; i < MT; ++i)
#pragma unroll
        for (int j = 0; j < 3; ++j) {
          acc[i][j] = __builtin_amdgcn_mfma_f32_16x16x32_bf16(ah[i], bh[j], acc[i][j], 0, 0, 0);
          acc[i][j] = __builtin_amdgcn_mfma_f32_16x16x32_bf16(ah[i], bl[j], acc[i][j], 0, 0, 0);
          acc[i][j] = __builtin_amdgcn_mfma_f32_16x16x32_bf16(al[i], bh[j], acc[i][j], 0, 0, 0);
        }
    }
    __syncthreads();
  }

#pragma unroll
  for (int j = 0; j < 3; ++j) {
    int jj = j0 + wn + j * 16 + r16;
    const float* ap = ADD ? (ADD + (long)(jj / 48) * 1536 + (jj % 3) * 512) : nullptr;
#pragma unroll
    for (int i = 0; i < MT; ++i) {
      int mm = m0 + wm + i * 16 + quad * 4;
      f32x4 v = acc[i][j];
      if (ap) { v.x += ap[mm]; v.y += ap[mm + 1]; v.z += ap[mm + 2]; v.w += ap[mm + 3]; }
      long o = (long)jj * M + mm;
      if (outmode != 1) *(f32x4*)(Cf + o) = v;
      if (outmode != 0) {
        ushort h[4], l[4];
        split_hl(v.x, h[0], l[0]); split_hl(v.y, h[1], l[1]);
        split_hl(v.z, h[2], l[2]); split_hl(v.w, h[3], l[3]);
        ushort4 hv = {h[0], h[1], h[2], h[3]}, lv = {l[0], l[1], l[2], l[3]};
        *(ushort4*)(CH + o) = hv;
        *(ushort4*)(CL + o) = lv;
      }
    }
  }
}

// ---------------------------------------------------------------------------
// Same GEMM but B staged directly from interleaved fp32 [b][K][3]:
// B[jj][k] = Bf[(jj/3)*3K + k*3 + (jj%3)], split to hi/lo during staging.
// ---------------------------------------------------------------------------
template<int MT>
__global__ __launch_bounds__(256) void gemm_hlf(
    const ushort* __restrict__ AH, const ushort* __restrict__ AL,
    const float* __restrict__ Bf,
    float* __restrict__ Cf, ushort* __restrict__ CH, ushort* __restrict__ CL,
    const float* __restrict__ ADD, int M, int K, int outmode)
{
  __shared__ __align__(16) ushort AsH[32 * MT * 72];
  __shared__ __align__(16) ushort AsL[32 * MT * 72];
  __shared__ __align__(16) ushort BsH[96 * 72];
  __shared__ __align__(16) ushort BsL[96 * 72];
  const int t = threadIdx.x;
  const int m0 = blockIdx.x * (32 * MT);
  const int j0 = blockIdx.y * 96;
  const int wid = t >> 6, lane = t & 63;
  const int wm = (wid >> 1) * (16 * MT), wn = (wid & 1) * 48;
  const int r16 = lane & 15, quad = lane >> 4;

  f32x4 acc[MT][3];
#pragma unroll
  for (int i = 0; i < MT; ++i)
#pragma unroll
    for (int j = 0; j < 3; ++j) acc[i][j] = (f32x4){0.f, 0.f, 0.f, 0.f};

  for (int k0 = 0; k0 < K; k0 += 64) {
#pragma unroll
    for (int r = 0; r < MT; ++r) {
      int f = r * 256 + t;
      int m = f >> 3, kc = f & 7;
      long off = (long)(m0 + m) * K + k0 + kc * 8;
      *(uint4*)(AsH + m * 72 + kc * 8) = *(const uint4*)(AH + off);
      *(uint4*)(AsL + m * 72 + kc * 8) = *(const uint4*)(AL + off);
    }
#pragma unroll
    for (int r = 0; r < 3; ++r) {
      int f = r * 256 + t;
      int n = f >> 3, kc = f & 7;
      int jj = j0 + n;
      int bq = jj / 3, xr = jj - bq * 3;
      const float* bp = Bf + (long)bq * (3 * K) + (long)(k0 + kc * 8) * 3 + xr;
      ushort hh[8], ll[8];
#pragma unroll
      for (int i = 0; i < 8; ++i) split_hl(bp[i * 3], hh[i], ll[i]);
      *(ushort4*)(BsH + n * 72 + kc * 8)     = *(ushort4*)hh;
      *(ushort4*)(BsH + n * 72 + kc * 8 + 4) = *(ushort4*)(hh + 4);
      *(ushort4*)(BsL + n * 72 + kc * 8)     = *(ushort4*)ll;
      *(ushort4*)(BsL + n * 72 + kc * 8 + 4) = *(ushort4*)(ll + 4);
    }
    __syncthreads();
#pragma unroll
    for (int kh = 0; kh < 2; ++kh) {
      bf16x8 ah[MT], al[MT], bh[3], bl[3];
#pragma unroll
      for (int i = 0; i < MT; ++i) {
        int ro = (wm + i * 16 + r16) * 72 + kh * 32 + quad * 8;
        ah[i] = *(const bf16x8*)(AsH + ro);
        al[i] = *(const bf16x8*)(AsL + ro);
      }
#pragma unroll
      for (int j = 0; j < 3; ++j) {
        int ro = (wn + j * 16 + r16) * 72 + kh * 32 + quad * 8;
        bh[j] = *(const bf16x8*)(BsH + ro);
        bl[j] = *(const bf16x8*)(BsL + ro);
      }
#pragma unroll
      for (int i = 0; i < MT; ++i)
#pragma unroll
        for (int j = 0; j < 3; ++j) {
          acc[i][j] = __builtin_amdgcn_mfma_f32_16x16x32_bf16(ah[i], bh[j], acc[i][j], 0, 0, 0);
          acc[i][j] = __builtin_amdgcn_mfma_f32_16x16x32_bf16(ah[i], bl[j], acc[i][j], 0, 0, 0);
          acc[i][j] = __builtin_amdgcn_mfma_f32_16x16x32_bf16(al[i], bh[j], acc[i][j], 0, 0, 0);
        }
    }
    __syncthreads();
  }

#pragma unroll
  for (int j = 0; j < 3; ++j) {
    int jj = j0 + wn + j * 16 + r16;
    const float* ap = ADD ? (ADD + (long)(jj / 48) * 1536 + (jj % 3) * 512) : nullptr;
#pragma unroll
    for (int i = 0; i < MT; ++i) {
      int mm = m0 + wm + i * 16 + quad * 4;
      f32x4 v = acc[i][j];
      if (ap) { v.x += ap[mm]; v.y += ap[mm + 1]; v.z += ap[mm + 2]; v.w += ap[mm + 3]; }
      long o = (long)jj * M + mm;
      if (outmode != 1) *(f32x4*)(Cf + o) = v;
      if (outmode != 0) {
        ushort h[4], l[4];
        split_hl(v.x, h[0], l[0]); split_hl(v.y, h[1], l[1]);
        split_hl(v.z, h[2], l[2]); split_hl(v.w, h[3], l[3]);
        ushort4 hv = {h[0], h[1], h[2], h[3]}, lv = {l[0], l[1], l[2], l[3]};
        *(ushort4*)(CH + o) = hv;
        *(ushort4*)(CL + o) = lv;
      }
    }
  }
}

// ---------------------------------------------------------------------------
// Edge kernel (R4-proven): msg hi/lo [e][3][512] in-place -> pv hi/lo.
// 4 edges/block, 1 wave/edge; fc_w3 read once per block.
// ---------------------------------------------------------------------------
__global__ __launch_bounds__(256) void edge_kernel(
    ushort* __restrict__ msgH, ushort* __restrict__ msgL,
    const float* __restrict__ edge_sh, const float* __restrict__ edge_scalars,
    const float* __restrict__ fc_w1, const float* __restrict__ fc_b1,
    const float* __restrict__ fc_w2, const float* __restrict__ fc_b2,
    const float* __restrict__ fc_w3, const float* __restrict__ fc_b3,
    const float* __restrict__ W_alpha, const float* __restrict__ ln_g,
    const float* __restrict__ ln_b, const float* __restrict__ alpha_dot,
    float* __restrict__ logits)
{
  __shared__ float esl[4][64];
  __shared__ float h1l[4][32];
  __shared__ float h2l[4][32];
  __shared__ float shl[4][4];
  __shared__ float pscl[4][512];
  __shared__ float smem_big[4 * 1536];   // (a) w1/w2/b stage (b) w values (c) W_alpha tile

  const int t = threadIdx.x;
  const int e0 = blockIdx.x * 4;
  const int W1O = 0, W2O = 2048, B1O = 3072, B2O = 3104;

  { int el = t >> 6, i = t & 63;
    esl[el][i] = edge_scalars[(long)(e0 + el) * 64 + i]; }
  if (t < 16) shl[t >> 2][t & 3] = edge_sh[(long)e0 * 4 + t];
#pragma unroll
  for (int r = 0; r < 13; ++r) {
    int l = t + 256 * r;
    if (l < 2048)      smem_big[W1O + l] = fc_w1[l];
    else if (l < 3072) smem_big[W2O + (l - 2048)] = fc_w2[l - 2048];
    else if (l < 3104) smem_big[B1O + (l - 3072)] = fc_b1[l - 3072];
    else if (l < 3136) smem_big[B2O + (l - 3104)] = fc_b2[l - 3104];
  }
  __syncthreads();

  if (t < 128) {
    int el = t >> 5, j = t & 31;
    float v = smem_big[B1O + j];
#pragma unroll 8
    for (int i = 0; i < 64; ++i) v += esl[el][i] * smem_big[W1O + i * 32 + j];
    h1l[el][j] = v / (1.f + expf(-v));
  }
  __syncthreads();
  if (t < 128) {
    int el = t >> 5, j = t & 31;
    float v = smem_big[B2O + j];
#pragma unroll 8
    for (int i = 0; i < 32; ++i) v += h1l[el][i] * smem_big[W2O + i * 32 + j];
    h2l[el][j] = v / (1.f + expf(-v));
  }
  __syncthreads();

  // Phase C: w[el][cc] = b3 + sum_j h2[el][j]*fc_w3[j][cc]; fc_w3 once per block
  {
    float wacc[4][6];
#pragma unroll
    for (int q = 0; q < 6; ++q) {
      float b3 = fc_b3[t + 256 * q];
#pragma unroll
      for (int el = 0; el < 4; ++el) wacc[el][q] = b3;
    }
#pragma unroll 4
    for (int j = 0; j < 32; ++j) {
      float h2e[4];
#pragma unroll
      for (int el = 0; el < 4; ++el) h2e[el] = h2l[el][j];
#pragma unroll
      for (int q = 0; q < 6; ++q) {
        float w3 = fc_w3[j * 1536 + t + 256 * q];
#pragma unroll
        for (int el = 0; el < 4; ++el) wacc[el][q] += h2e[el] * w3;
      }
    }
    __syncthreads();
#pragma unroll
    for (int q = 0; q < 6; ++q)
#pragma unroll
      for (int el = 0; el < 4; ++el)
        smem_big[el * 1536 + t + 256 * q] = wacc[el][q];
  }
  __syncthreads();

  const int el = t >> 6, lane = t & 63;
  const long ebase = (long)(e0 + el) * 1536;
  const float s  = shl[el][0], vx = shl[el][1], vy = shl[el][2], vz = shl[el][3];
  const float* wle = smem_big + el * 1536;

#pragma unroll
  for (int i = 0; i < 8; ++i) {
    int c = lane + 64 * i;
    float m0 = bf2f(msgH[ebase + c])        + bf2f(msgL[ebase + c]);
    float m1 = bf2f(msgH[ebase + 512 + c])  + bf2f(msgL[ebase + 512 + c]);
    float m2 = bf2f(msgH[ebase + 1024 + c]) + bf2f(msgL[ebase + 1024 + c]);
    float w0 = wle[c], w1 = wle[512 + c], w2 = wle[1024 + c];
    float dotv = m0 * vx + m1 * vy + m2 * vz;
    pscl[el][c] = w0 * dotv * RS3;
    float cx = m1 * vz - m2 * vy;
    float cy = m2 * vx - m0 * vz;
    float cz = m0 * vy - m1 * vx;
    float f1 = w1 * s;
    float f2 = w2 * RS2;
    float p0 = f1 * m0 + f2 * cx;
    float p1 = f1 * m1 + f2 * cy;
    float p2 = f1 * m2 + f2 * cz;
    ushort h, lo;
    split_hl(p0, h, lo); msgH[ebase + c] = h;        msgL[ebase + c] = lo;
    split_hl(p1, h, lo); msgH[ebase + 512 + c] = h;  msgL[ebase + 512 + c] = lo;
    split_hl(p2, h, lo); msgH[ebase + 1024 + c] = h; msgL[ebase + 1024 + c] = lo;
  }
  __syncthreads();

  float accm = 0.f;
  for (int ch = 0; ch < 8; ++ch) {
#pragma unroll
    for (int r = 0; r < 16; ++r) {
      int l = t + 256 * r;
      smem_big[l] = W_alpha[(long)(ch * 64) * 64 + l];
    }
    __syncthreads();
#pragma unroll 8
    for (int cl = 0; cl < 64; ++cl)
      accm += pscl[el][ch * 64 + cl] * smem_big[cl * 64 + lane];
    __syncthreads();
  }

  float s1 = wave_sum64(accm);
  float s2 = wave_sum64(accm * accm);
  float mu  = s1 * (1.f / 64.f);
  float var = s2 * (1.f / 64.f) - mu * mu;
  float aln = (accm - mu) * rsqrtf(var + EPS) * ln_g[lane] + ln_b[lane];
  float act = 0.6f * aln + 0.4f * aln * tanhf(0.5f * aln);
  float p = act * alpha_dot[lane];
#pragma unroll
  for (int d2 = 4; d2 > 0; d2 >>= 1) p += __shfl_down(p, d2, 8);
  if ((lane & 7) == 0) logits[(long)(e0 + el) * 8 + (lane >> 3)] = p;
}

// ---------------------------------------------------------------------------
// Softmax over k + aggregation, IN PLACE per-block slice.
// pvagg row (n,x) at ushort offset n*24576 + x*4096 + h*512 + c.
// ---------------------------------------------------------------------------
__global__ __launch_bounds__(256) void attn_agg(
    const float* __restrict__ logits, ushort* __restrict__ pvH, ushort* __restrict__ pvL)
{
  __shared__ float atl[16][8];
  const int n = blockIdx.x, t = threadIdx.x;
  if (t < 128) {
    int k = t >> 3, h = t & 7;
    atl[k][h] = logits[((long)n * 16 + k) * 8 + h];
  }
  __syncthreads();
  if (t < 8) {
    int h = t;
    float mx = -1e30f;
    for (int k = 0; k < 16; ++k) mx = fmaxf(mx, atl[k][h]);
    float ex[16]; float sm = 0.f;
    for (int k = 0; k < 16; ++k) { ex[k] = expf(atl[k][h] - mx); sm += ex[k]; }
    float inv = 1.f / sm;
    for (int k = 0; k < 16; ++k) atl[k][h] = ex[k] * inv;
  }
  __syncthreads();

  float acc[6][8];
#pragma unroll
  for (int i = 0; i < 6; ++i)
#pragma unroll
    for (int h = 0; h < 8; ++h) acc[i][h] = 0.f;

  const long sb = (long)n * 24576;
  for (int k = 0; k < 16; ++k) {
    float aw[8];
#pragma unroll
    for (int h = 0; h < 8; ++h) aw[h] = atl[k][h];
#pragma unroll
    for (int i = 0; i < 6; ++i) {
      long off = sb + k * 1536 + t + 256 * i;
      float mval = bf2f(pvH[off]) + bf2f(pvL[off]);
#pragma unroll
      for (int h = 0; h < 8; ++h) acc[i][h] += aw[h] * mval;
    }
  }
  __syncthreads();
#pragma unroll
  for (int i = 0; i < 6; ++i) {
    int l = t + 256 * i;
    int x = l >> 9, c = l & 511;
#pragma unroll
    for (int h = 0; h < 8; ++h) {
      ushort hh, ll; split_hl(acc[i][h], hh, ll);
      long off = sb + x * 4096 + h * 512 + c;
      pvH[off] = hh; pvL[off] = ll;
    }
  }
}

// ---------------------------------------------------------------------------
// vn_ln on xC layout. mode 0: outf fp32 xC + hi/lo xC; mode 1: outf [c*3+x]
// ---------------------------------------------------------------------------
__global__ __launch_bounds__(256) void vn_ln_x(
    const float* __restrict__ A, const float* __restrict__ Bp,
    const float* __restrict__ g, const float* __restrict__ bb,
    float* __restrict__ outf, ushort* __restrict__ outH, ushort* __restrict__ outL,
    int mode)
{
  const int n = blockIdx.x, t = threadIdx.x;
  const long base = (long)n * 1536;
  float xv[2][3], nrm[2];
#pragma unroll
  for (int q = 0; q < 2; ++q) {
    int c = t + 256 * q;
    float ssq = 0.f;
#pragma unroll
    for (int x = 0; x < 3; ++x) {
      float v = A[base + x * 512 + c] + Bp[base + x * 512 + c];
      xv[q][x] = v; ssq += v * v;
    }
    nrm[q] = sqrtf(ssq + EPS);
  }
  float s1 = nrm[0] + nrm[1];
  float s2 = nrm[0] * nrm[0] + nrm[1] * nrm[1];
  s1 = wave_sum64(s1); s2 = wave_sum64(s2);
  __shared__ float red[8];
  int wid = t >> 6;
  if ((t & 63) == 0) { red[wid] = s1; red[4 + wid] = s2; }
  __syncthreads();
  float S1 = red[0] + red[1] + red[2] + red[3];
  float S2 = red[4] + red[5] + red[6] + red[7];
  float mu  = S1 * (1.f / 512.f);
  float var = S2 * (1.f / 512.f) - mu * mu;
  float rstd = rsqrtf(var + EPS);
#pragma unroll
  for (int q = 0; q < 2; ++q) {
    int c = t + 256 * q;
    float ln = (nrm[q] - mu) * rstd * g[c] + bb[c];
    float sc = ln / nrm[q];
    if (mode == 0) {
#pragma unroll
      for (int x = 0; x < 3; ++x) {
        float v = xv[q][x] * sc;
        outf[base + x * 512 + c] = v;
        ushort h, lo; split_hl(v, h, lo);
        outH[base + x * 512 + c] = h;
        outL[base + x * 512 + c] = lo;
      }
    } else {
#pragma unroll
      for (int x = 0; x < 3; ++x)
        outf[base + c * 3 + x] = xv[q][x] * sc;
    }
  }
}

// ---------------------------------------------------------------------------
// Gate on fp32 y, dvec (xC [n][3][2048]) -> gy hi/lo
// ---------------------------------------------------------------------------
__global__ __launch_bounds__(256) void gate_hl(
    const float* __restrict__ y, const float* __restrict__ dv,
    ushort* __restrict__ gh, ushort* __restrict__ gl)
{
  long idx = (long)blockIdx.x * 256 + threadIdx.x;   // over 1024*2048
  long n = idx >> 11; int o = idx & 2047;
  long b = n * 6144 + o;
  float y0 = y[b], y1 = y[b + 2048], y2 = y[b + 4096];
  float d0 = dv[b], d1 = dv[b + 2048], d2 = dv[b + 4096];
  float dot = y0 * d0 + y1 * d1 + y2 * d2;
  if (dot < 0.f) {
    float dnn = d0 * d0 + d1 * d1 + d2 * d2 + EPS;
    float coef = 0.8f * dot / dnn;
    y0 -= coef * d0; y1 -= coef * d1; y2 -= coef * d2;
  }
  ushort h, lo;
  split_hl(y0, h, lo); gh[b] = h;        gl[b] = lo;
  split_hl(y1, h, lo); gh[b + 2048] = h; gl[b + 2048] = lo;
  split_hl(y2, h, lo); gh[b + 4096] = h; gl[b + 4096] = lo;
}

// ---------------------------------------------------------------------------
extern "C" void kernel_launch(void* const* d_in, const int* in_sizes, int n_in,
                              void* d_out, int out_size, void* d_ws, size_t ws_size,
                              hipStream_t stream)
{
  const float* tgt          = (const float*)d_in[0];
  const float* memory       = (const float*)d_in[1];
  const float* edge_sh      = (const float*)d_in[2];
  const float* edge_scalars = (const float*)d_in[3];
  const float* W_src   = (const float*)d_in[4];
  const float* W_dst   = (const float*)d_in[5];
  const float* fc_w1   = (const float*)d_in[6];
  const float* fc_b1   = (const float*)d_in[7];
  const float* fc_w2   = (const float*)d_in[8];
  const float* fc_b2   = (const float*)d_in[9];
  const float* fc_w3   = (const float*)d_in[10];
  const float* fc_b3   = (const float*)d_in[11];
  const float* W_alpha = (const float*)d_in[12];
  const float* ln_a_g  = (const float*)d_in[13];
  const float* ln_a_b  = (const float*)d_in[14];
  const float* alpha_dot = (const float*)d_in[15];
  const float* W_value = (const float*)d_in[16];
  const float* W_proj  = (const float*)d_in[17];
  const float* n1_g    = (const float*)d_in[18];
  const float* n1_b    = (const float*)d_in[19];
  const float* n2_g    = (const float*)d_in[20];
  const float* n2_b    = (const float*)d_in[21];
  const float* W_ff1   = (const float*)d_in[22];
  const float* W_ffd   = (const float*)d_in[23];
  const float* W_ff2   = (const float*)d_in[24];
  float* out = (float*)d_out;

  char* ws = (char*)d_ws;
  // Region A [0, 100663296): msg hi/lo -> pv (in-place) -> pvagg; later FF bufs
  ushort* msgH = (ushort*)(ws + 0);          // 50,331,648 B
  ushort* msgL = (ushort*)(ws + 50331648);   // 50,331,648 B
  float*  yf   = (float*)(ws + 0);           // 25,165,824 B (after pvagg dead)
  ushort* yH   = (ushort*)(ws + 25165824);   // 12,582,912
  ushort* yL   = (ushort*)(ws + 37748736);   // 12,582,912
  float*  dvf  = (float*)(ws + 50331648);    // 25,165,824
  ushort* gyH  = (ushort*)(ws + 75497472);   // 12,582,912
  ushort* gyL  = (ushort*)(ws + 88080384);   // 12,582,912
  // Fixed
  float*  tvx  = (float*)(ws + 100663296);   // 6,291,456
  float*  nb2  = (float*)(ws + 106954752);   // 6,291,456
  // x1 region
  float*  x1f   = (float*)(ws + 113246208);  // 6,291,456
  ushort* x1H   = (ushort*)(ws + 119537664); // 3,145,728
  ushort* x1L   = (ushort*)(ws + 122683392); // 3,145,728
  float*  logits = (float*)(ws + 125829120); // 524,288
  // Weights
  ushort* WH    = (ushort*)(ws + 126353408); // 13,631,488
  ushort* WL    = (ushort*)(ws + 139984896); // 13,631,488
  ushort* wcH   = (ushort*)(ws + 153616384); // 4,194,304
  ushort* wcL   = (ushort*)(ws + 157810688); // 4,194,304  -> peak 162,004,992 B

  const long SRC = 0, DST = 262144, FF1 = 524288, FFD = 1572864, FF2 = 5767168;

  // prep
  cvt_weights_hl<<<3328, 256, 0, stream>>>(W_src, W_dst, W_ff1, W_ffd, W_ff2, WH, WL);
  wcomb_kernel<<<dim3(64, 8), 256, 0, stream>>>(W_proj, W_value, wcH, wcL);

  // 1. tv = W_dst @ tgt  (fp32 B direct)
  gemm_hlf<2><<<dim3(8, 32), 256, 0, stream>>>(WH + DST, WL + DST, tgt,
      tvx, nullptr, nullptr, nullptr, 512, 512, 0);

  // 2. msg = W_src @ memory + tv  (fp32 B direct, single dispatch, hi/lo out)
  gemm_hlf<4><<<dim3(4, 512), 256, 0, stream>>>(WH + SRC, WL + SRC, memory,
      nullptr, msgH, msgL, tvx, 512, 512, 1);

  // 3. edge: MLP, p_sc, pv in place, logits  (R4-proven structure)
  edge_kernel<<<4096, 256, 0, stream>>>(msgH, msgL, edge_sh, edge_scalars,
      fc_w1, fc_b1, fc_w2, fc_b2, fc_w3, fc_b3, W_alpha, ln_a_g, ln_a_b, alpha_dot, logits);

  // 4. softmax + aggregate -> pvagg hi/lo in place
  attn_agg<<<1024, 256, 0, stream>>>(logits, msgH, msgL);

  // 5. out3 = Wcomb @ pvagg  (fp32), pvagg bnp = 24576
  gemm_hl<2><<<dim3(8, 32), 256, 0, stream>>>(wcH, wcL, msgH, msgL,
      nb2, nullptr, nullptr, nullptr, 512, 4096, 24576, 0);

  // 6. x1 = vn_ln(tv + out3): fp32 + hi/lo
  vn_ln_x<<<1024, 256, 0, stream>>>(tvx, nb2, n1_g, n1_b, x1f, x1H, x1L, 0);

  // 7. y = W_ff1 @ x1  (fp32 + hi/lo out; region A dead)
  gemm_hl<4><<<dim3(16, 32), 256, 0, stream>>>(WH + FF1, WL + FF1, x1H, x1L,
      yf, yH, yL, nullptr, 2048, 512, 1536, 2);

  // 8. dvec = W_ffd @ y  (fp32)
  gemm_hl<4><<<dim3(16, 32), 256, 0, stream>>>(WH + FFD, WL + FFD, yH, yL,
      dvf, nullptr, nullptr, nullptr, 2048, 2048, 6144, 0);

  // 9. gate -> gy hi/lo
  gate_hl<<<8192, 256, 0, stream>>>(yf, dvf, gyH, gyL);

  // 10. y2 = W_ff2 @ gy  (fp32, reuse nb2)
  gemm_hl<2><<<dim3(8, 32), 256, 0, stream>>>(WH + FF2, WL + FF2, gyH, gyL,
      nb2, nullptr, nullptr, nullptr, 512, 2048, 6144, 0);

  // 11. out = vn_ln(x1 + y2) -> interleaved [n][c][3]
  vn_ln_x<<<1024, 256, 0, stream>>>(x1f, nb2, n2_g, n2_b, out, nullptr, nullptr, 1);
}